// Round 7
// baseline (289.494 us; speedup 1.0000x reference)
//
#include <hip/hip_runtime.h>

#define B_ 4
#define T_ 2048
#define C_ 1024
#define H_ 4
#define D_ 256
#define M_ (B_*T_)      /* 8192 */
#define N1_ (4*C_)      /* 4096 */
#define K_ C_           /* 1024 */
#define LANES_ (B_*C_)  /* 4096 */
#define CHUNK_ 32
#define NCHUNK_ (T_/CHUNK_)  /* 64 */

typedef unsigned short u16;
typedef unsigned int u32;
typedef __bf16 bf16x8 __attribute__((ext_vector_type(8)));
typedef float f32x4 __attribute__((ext_vector_type(4)));
typedef float vf4 __attribute__((ext_vector_type(4)));
typedef unsigned short u16x4 __attribute__((ext_vector_type(4)));
typedef unsigned short u16x8 __attribute__((ext_vector_type(8)));

__device__ __forceinline__ u16 f2bf(float f) {
  union { float f; u32 u; } v; v.f = f;
  u32 u = v.u;
  u32 r = (u + 0x7FFFu + ((u >> 16) & 1u)) >> 16;
  return (u16)r;
}
__device__ __forceinline__ float b2f(u16 h) {
  union { u32 u; float f; } v; v.u = ((u32)h) << 16;
  return v.f;
}

#define NCAST_ ((N1_*K_) / 2048)   /* 2048 blocks for wx_w cast */

// ---------------- merged prologue: wx_w cast + conv+SiLU ----------------
__global__ void prep_kernel(const float* __restrict__ wx_w,
                            u16* __restrict__ w1p,
                            const float* __restrict__ x, const float* __restrict__ cw,
                            const float* __restrict__ cb, u16* __restrict__ xc,
                            float* __restrict__ stats) {
  if (blockIdx.x < NCAST_) {
    int i8 = (blockIdx.x * 256 + threadIdx.x) * 8;
    int n = i8 >> 10, k8 = i8 & 1023;
    const float* src = wx_w + (size_t)(((n & 3) << 10) | (n >> 2)) * K_ + k8;
    vf4 a = *(const vf4*)src;
    vf4 b = *(const vf4*)(src + 4);
    u16x8 o;
#pragma unroll
    for (int j = 0; j < 4; ++j) { o[j] = f2bf(a[j]); o[j + 4] = f2bf(b[j]); }
    *(u16x8*)(w1p + i8) = o;
    return;
  }
  if (blockIdx.x == NCAST_ && threadIdx.x < 32) stats[threadIdx.x] = 0.f;
  int i4 = ((blockIdx.x - NCAST_) * 256 + threadIdx.x) * 4;
  int c = i4 & (C_ - 1);
  int t = (i4 >> 10) & (T_ - 1);
  vf4 acc = *(const vf4*)(cb + c);
  vf4 w0 = *(const vf4*)(cw + (size_t)c * 4);
  vf4 w1 = *(const vf4*)(cw + (size_t)(c + 1) * 4);
  vf4 w2v = *(const vf4*)(cw + (size_t)(c + 2) * 4);
  vf4 w3 = *(const vf4*)(cw + (size_t)(c + 3) * 4);
#pragma unroll
  for (int k = 0; k < 4; ++k) {
    if (t - 3 + k >= 0) {
      vf4 xv = *(const vf4*)(x + (size_t)i4 + (size_t)(k - 3) * C_);
      acc[0] = fmaf(w0[k], xv[0], acc[0]);
      acc[1] = fmaf(w1[k], xv[1], acc[1]);
      acc[2] = fmaf(w2v[k], xv[2], acc[2]);
      acc[3] = fmaf(w3[k], xv[3], acc[3]);
    }
  }
  u16x4 o;
#pragma unroll
  for (int j = 0; j < 4; ++j) {
    float s = acc[j] / (1.f + __expf(-acc[j]));
    o[j] = f2bf(s);
  }
  *(u16x4*)(xc + i4) = o;
}

// ---------------- bf16 MFMA GEMM, C[m][n] = sum_k A[m][k] * Bw[n][k] ----------------
// Verified config __launch_bounds__(256,3).  Round-7 change: T1 XCD-bijective
// block swizzle (grid%8==0 in both uses): each XCD owns a contiguous 8-M-tile
// band (A-band 2 MB, L2-resident) x all N, bn fastest.  Mechanism: kill the
// 3x A-panel overfetch (FETCH 74 MB vs 25 MB compulsory) from round-robin
// XCD thrash.  EPI 0: gates epilogue + fused passA.  EPI 1: GN pre-folded
// per-batch weights/bias + residual (each XCD band lies in one batch).
template <int EPI>
__global__ __launch_bounds__(256, 3)
void gemm_bt(const u16* __restrict__ A, const u16* __restrict__ Bw,
             const float* __restrict__ bias, const float* __restrict__ resid,
             u16* __restrict__ obf, float* __restrict__ of32,
             f32x4* __restrict__ sSum, int M, int N, int K)
{
  __shared__ __align__(16) u16 smem[128 * 136];   // 34.8 KB; staging uses first 32 KB
  u16* a_s = smem;
  u16* b_s = smem + 128 * 64;

  const int tid  = threadIdx.x;
  const int lane = tid & 63;
  const int l15  = lane & 15;
  const int q    = lane >> 4;
  const int wave = tid >> 6;
  const int wm   = (wave >> 1) * 64;
  const int wn   = (wave & 1) * 64;

  // XCD-bijective swizzle: bid -> (bid&7)*chunk + bid>>3 (nwg % 8 == 0)
  const int nbx = gridDim.x;
  const int nwg = nbx * gridDim.y;
  const int bid = blockIdx.y * nbx + blockIdx.x;
  const int wg  = (bid & 7) * (nwg >> 3) + (bid >> 3);
  const int bm  = (wg / nbx) * 128;
  const int bn  = (wg % nbx) * 128;

  if (EPI == 1) {
    // per-batch folded weights/bias (each 128-row M-tile lies in one batch)
    int batch = bm >> 11;
    Bw   += (size_t)batch * N * K;
    bias += (size_t)batch << 10;
  }

  const int srow   = wave * 8 + (lane >> 3);
  const int schunk = lane & 7;

  // per-thread bias (columns depend only on sn)
  float bias4[4];
#pragma unroll
  for (int sn = 0; sn < 4; ++sn) {
    int gcol = bn + wn + sn * 16 + l15;
    bias4[sn] = (EPI == 0) ? bias[((gcol & 3) << 10) | (gcol >> 2)] : bias[gcol];
  }
  const bool zlane = (EPI == 0) && ((l15 & 3) == 2);

  f32x4 acc[4][4];
#pragma unroll
  for (int i = 0; i < 4; ++i)
#pragma unroll
    for (int j = 0; j < 4; ++j) acc[i][j] = (f32x4){0.f, 0.f, 0.f, 0.f};

  for (int k0 = 0; k0 < K; k0 += 64) {
#pragma unroll
    for (int i = 0; i < 4; ++i) {
      int r = i * 32 + srow;
      int lc = schunk ^ (r & 7);
      const u16* ga = A  + (size_t)(bm + r) * K + k0 + lc * 8;
      const u16* gb = Bw + (size_t)(bn + r) * K + k0 + lc * 8;
      __builtin_amdgcn_global_load_lds(
          (const __attribute__((address_space(1))) u32*)ga,
          (__attribute__((address_space(3))) u32*)&a_s[(i * 32 + wave * 8) * 64],
          16, 0, 0);
      __builtin_amdgcn_global_load_lds(
          (const __attribute__((address_space(1))) u32*)gb,
          (__attribute__((address_space(3))) u32*)&b_s[(i * 32 + wave * 8) * 64],
          16, 0, 0);
    }
    __syncthreads();
#pragma unroll
    for (int kk = 0; kk < 64; kk += 32) {
      const int kc = kk >> 3;
      bf16x8 af[4], bfr[4];
#pragma unroll
      for (int s = 0; s < 4; ++s) {
        int ra = wm + s * 16 + l15;
        int ph = (kc + q) ^ (ra & 7);
        af[s] = *(const bf16x8*)&a_s[ra * 64 + ph * 8];
      }
#pragma unroll
      for (int s = 0; s < 4; ++s) {
        int rb = wn + s * 16 + l15;
        int ph = (kc + q) ^ (rb & 7);
        bfr[s] = *(const bf16x8*)&b_s[rb * 64 + ph * 8];
      }
#pragma unroll
      for (int sm = 0; sm < 4; ++sm)
#pragma unroll
        for (int sn = 0; sn < 4; ++sn)
          acc[sm][sn] = __builtin_amdgcn_mfma_f32_16x16x32_bf16(af[sm], bfr[sn], acc[sm][sn], 0, 0, 0);
    }
    __syncthreads();
  }

  if (EPI == 0) {
    // stash bf16 tile in LDS (stride 136 u16 = 272 B, 16B-aligned rows)
#pragma unroll
    for (int smi = 0; smi < 4; ++smi) {
#pragma unroll
      for (int r = 0; r < 4; ++r) {
        int lrow = wm + smi * 16 + q * 4 + r;
#pragma unroll
        for (int sni = 0; sni < 4; ++sni) {
          int lcol = wn + sni * 16 + l15;
          float v = acc[smi][sni][r] + bias4[sni];
          if (zlane) {
            float e = __expf(2.f * v);
            v = (e - 1.f) / (e + 1.f);
          }
          smem[lrow * 136 + lcol] = f2bf(v);
        }
      }
    }
    __syncthreads();
    // vectorized global stores: 8 x 16B per thread
#pragma unroll
    for (int it = 0; it < 8; ++it) {
      int flat = it * 256 + tid;               // 0..2047
      int row = flat >> 4;
      int ch  = flat & 15;
      u16x8 vv = *(const u16x8*)&smem[row * 136 + ch * 8];
      *(u16x8*)(obf + (size_t)(bm + row) * N + bn + ch * 8) = vv;
    }
    // fused passA: 32 channels x 4 chunks of 32 timesteps
    if (tid < 128) {
      int ch = tid & 31, ck = tid >> 5;
      const u16* sp = smem + (ck * 32) * 136 + ch * 4;
      float F = 0.f, Mx = -1e30f, aBc = 0.f, aBn = 0.f;
#pragma unroll 8
      for (int t = 0; t < CHUNK_; ++t) {
        u16x4 gv = *(const u16x4*)(sp + t * 136);
        float i_t = b2f(gv[0]), f_t = b2f(gv[1]), z_t = b2f(gv[2]);
        float Mf = Mx + f_t;
        float Mn = fmaxf(Mf, i_t);
        float ea = __expf(Mf - Mn), eb = __expf(i_t - Mn);
        aBc = ea * aBc + eb * z_t;
        aBn = ea * aBn + eb;
        F += f_t; Mx = Mn;
      }
      int b = bm >> 11;
      int s = ((bm & 2047) >> 5) + ck;
      int cg = (bn >> 2) + ch;
      sSum[(size_t)s * LANES_ + b * C_ + cg] = (f32x4){F, Mx, aBc, aBn};
    }
  } else {
    // two half-tiles through LDS as fp32 (64 x 132 floats = 33.8 KB)
    float* fs = (float*)smem;
#pragma unroll
    for (int h = 0; h < 2; ++h) {
      __syncthreads();
#pragma unroll
      for (int smi2 = 0; smi2 < 2; ++smi2) {
        int smi = 2 * h + smi2;
#pragma unroll
        for (int r = 0; r < 4; ++r) {
          int slot = (wm >> 1) + smi2 * 16 + q * 4 + r;   // 0..63
#pragma unroll
          for (int sni = 0; sni < 4; ++sni) {
            int lcol = wn + sni * 16 + l15;
            fs[slot * 132 + lcol] = acc[smi][sni][r] + bias4[sni];
          }
        }
      }
      __syncthreads();
#pragma unroll
      for (int it = 0; it < 8; ++it) {
        int flat = it * 256 + tid;             // 0..2047
        int slot = flat >> 5;                  // 0..63
        int c4 = (flat & 31) * 4;
        int absrow = bm + ((slot & 32) << 1) + (h << 5) + (slot & 31);
        vf4 v = *(const vf4*)&fs[slot * 132 + c4];
        vf4 rv = *(const vf4*)(resid + (size_t)absrow * N + bn + c4);
        v[0] += rv[0]; v[1] += rv[1]; v[2] += rv[2]; v[3] += rv[3];
        *(vf4*)(of32 + (size_t)absrow * N + bn + c4) = v;
      }
    }
  }
}

// ---------------- prefix: fold 64 chunk summaries per lane; float4-packed ----------------
__global__ void scan_prefix(const f32x4* __restrict__ sSum, f32x4* __restrict__ iSt) {
  int l = blockIdx.x * 256 + threadIdx.x;       // 0..4095
  float ct = 0.f, nt = 1.f, mt = 0.f;           // reference init (c=0, n=1, m=0)
#pragma unroll 8
  for (int s = 0; s < NCHUNK_; ++s) {
    int idx = s * LANES_ + l;
    f32x4 S = sSum[idx];
    iSt[idx] = (f32x4){ct, nt, mt, 0.f};
    float mf = mt + S[0];
    float mn = fmaxf(mf, S[1]);
    float a = __expf(mf - mn);
    float bcoef = __expf(S[1] - mn);
    ct = a * ct + bcoef * S[2];
    nt = a * nt + bcoef * S[3];
    mt = mn;
  }
}

// ---------------- passB: exact reference replay per chunk + fused GN stats ----------------
__global__ void scan_passB(const u16* __restrict__ gates, const f32x4* __restrict__ iSt,
                           u16* __restrict__ h, float* __restrict__ stats) {
  int tid = blockIdx.x * 256 + threadIdx.x;
  int lp = tid & 2047;
  int s = tid >> 11;
  int b = lp >> 9;
  int c2 = (lp & 511) * 2;
  const u16* g = gates + ((size_t)(b * T_ + s * CHUNK_) * C_ + c2) * 4;
  u16* hp = h + (size_t)(b * T_ + s * CHUNK_) * C_ + c2;
  int idx = s * LANES_ + b * C_ + c2;
  f32x4 S0 = iSt[idx], S1 = iSt[idx + 1];
  float cc0 = S0[0], nn0 = S0[1], mm0 = S0[2];
  float cc1 = S1[0], nn1 = S1[1], mm1 = S1[2];
  float ls = 0.f, lq = 0.f;
#pragma unroll 4
  for (int t = 0; t < CHUNK_; ++t) {
    u16x8 gv = *(const u16x8*)(g + (size_t)t * C_ * 4);   // [i0 f0 z0 o0 i1 f1 z1 o1]
    float h0, h1;
    {
      float i_t = b2f(gv[0]), f_t = b2f(gv[1]), z_t = b2f(gv[2]), o_t = b2f(gv[3]);
      float m_new = fmaxf(f_t + mm0, i_t);
      float i_p = __expf(i_t - m_new);
      float f_p = __expf(f_t + mm0 - m_new);
      cc0 = f_p * cc0 + i_p * z_t;
      nn0 = f_p * nn0 + i_p;
      mm0 = m_new;
      float sig_o = 1.f / (1.f + __expf(-o_t));
      h0 = sig_o * (cc0 / (nn0 + 1e-6f));
    }
    {
      float i_t = b2f(gv[4]), f_t = b2f(gv[5]), z_t = b2f(gv[6]), o_t = b2f(gv[7]);
      float m_new = fmaxf(f_t + mm1, i_t);
      float i_p = __expf(i_t - m_new);
      float f_p = __expf(f_t + mm1 - m_new);
      cc1 = f_p * cc1 + i_p * z_t;
      nn1 = f_p * nn1 + i_p;
      mm1 = m_new;
      float sig_o = 1.f / (1.f + __expf(-o_t));
      h1 = sig_o * (cc1 / (nn1 + 1e-6f));
    }
    u16 hb0 = f2bf(h0), hb1 = f2bf(h1);
    float v0 = b2f(hb0), v1 = b2f(hb1);
    ls += v0 + v1; lq += v0 * v0 + v1 * v1;
    *(u32*)(hp + (size_t)t * C_) = (u32)hb0 | ((u32)hb1 << 16);
  }
  __shared__ float rs[256], rq[256];
  int thr = threadIdx.x;
  rs[thr] = ls; rq[thr] = lq;
  __syncthreads();
  for (int off = 64; off > 0; off >>= 1) {
    if ((thr & 127) < off) { rs[thr] += rs[thr + off]; rq[thr] += rq[thr + off]; }
    __syncthreads();
  }
  if ((thr & 127) == 0) {
    int grp = b * 4 + (c2 >> 8);
    atomicAdd(&stats[grp * 2 + 0], rs[thr]);
    atomicAdd(&stats[grp * 2 + 1], rq[thr]);
  }
}

// ---------------- GN fold: w2p[b][o][c] = bf16(rstd*gn_w[c]*out_w[o][c]),
//                  biasp[b][o] = out_b[o] + sum_c (gn_b[c]-mean*rstd*gn_w[c])*out_w[o][c]
__global__ void gn_fold(const float* __restrict__ out_w, const float* __restrict__ stats,
                        const float* __restrict__ gn_w, const float* __restrict__ gn_b,
                        const float* __restrict__ out_b,
                        u16* __restrict__ w2p, float* __restrict__ biasp) {
  const int batch = blockIdx.y;
  const int o = blockIdx.x * 16 + (threadIdx.x >> 4);
  const int seg = threadIdx.x & 15;
  const int c0 = seg * 64;                        // 64-col span, never crosses a group
  const int grp = batch * 4 + (c0 >> 8);
  const float inv_n = 1.f / (float)(T_ * D_);
  float mean = stats[grp * 2 + 0] * inv_n;
  float var  = stats[grp * 2 + 1] * inv_n - mean * mean;
  float rstd = rsqrtf(var + 1e-5f);
  const float* wrow = out_w + (size_t)o * C_;
  u16* wdst = w2p + ((size_t)batch * C_ + o) * C_;
  float acc = 0.f;
#pragma unroll 4
  for (int c = c0; c < c0 + 64; c += 4) {
    vf4 w  = *(const vf4*)(wrow + c);
    vf4 gw = *(const vf4*)(gn_w + c);
    vf4 gb = *(const vf4*)(gn_b + c);
    u16x4 ov;
#pragma unroll
    for (int j = 0; j < 4; ++j) {
      float s1 = rstd * gw[j];
      ov[j] = f2bf(s1 * w[j]);
      acc = fmaf(gb[j] - mean * s1, w[j], acc);
    }
    *(u16x4*)(wdst + c) = ov;
  }
  __shared__ float red[256];
  red[threadIdx.x] = acc;
  __syncthreads();
  for (int off = 8; off > 0; off >>= 1) {
    if (seg < off) red[threadIdx.x] += red[threadIdx.x + off];
    __syncthreads();
  }
  if (seg == 0) biasp[batch * C_ + o] = out_b[o] + red[threadIdx.x];
}

extern "C" void kernel_launch(void* const* d_in, const int* in_sizes, int n_in,
                              void* d_out, int out_size, void* d_ws, size_t ws_size,
                              hipStream_t stream) {
  const float* x      = (const float*)d_in[0];
  const float* conv_w = (const float*)d_in[1];
  const float* conv_b = (const float*)d_in[2];
  const float* wx_w   = (const float*)d_in[3];
  const float* wx_b   = (const float*)d_in[4];
  const float* gn_w   = (const float*)d_in[5];
  const float* gn_b   = (const float*)d_in[6];
  const float* out_w  = (const float*)d_in[7];
  const float* out_b  = (const float*)d_in[8];
  float* out = (float*)d_out;

  char* p = (char*)d_ws;
  u16* xc    = (u16*)p; p += (size_t)M_ * K_ * 2;      // 16.8 MB
  u16* w1    = (u16*)p; p += (size_t)N1_ * K_ * 2;     // 8.4 MB (permuted)
  u16* gts   = (u16*)p; p += (size_t)M_ * N1_ * 2;     // 67.1 MB (interleaved c*4+g)
  u16* hb    = (u16*)p; p += (size_t)M_ * C_ * 2;      // 16.8 MB
  u16* w2p   = (u16*)p; p += (size_t)B_ * C_ * C_ * 2; // 8.4 MB (per-batch folded)
  float* biasp = (float*)p; p += (size_t)B_ * C_ * 4;  // 16 KB
  float* stats = (float*)p; p += 256;
  const int nsum = LANES_ * NCHUNK_;                   // 256K
  f32x4* sSum = (f32x4*)p; p += (size_t)nsum * 16;     // 4 MB
  f32x4* iSt  = (f32x4*)p; p += (size_t)nsum * 16;     // 4 MB

  // merged prologue: wx_w cast + conv/silu (also zeroes stats)
  prep_kernel<<<NCAST_ + (M_ * C_) / 1024, 256, 0, stream>>>(
      wx_w, w1, x, conv_w, conv_b, xc, stats);

  // gates GEMM + fused passA (XCD-swizzled)
  gemm_bt<0><<<dim3(N1_ / 128, M_ / 128), 256, 0, stream>>>(
      xc, w1, wx_b, nullptr, gts, nullptr, sSum, M_, N1_, K_);

  // prefix + replay
  scan_prefix<<<LANES_ / 256, 256, 0, stream>>>(sSum, iSt);
  scan_passB<<<(2048 * NCHUNK_) / 256, 256, 0, stream>>>(gts, iSt, hb, stats);

  // fold GroupNorm into per-batch output weights + bias
  gn_fold<<<dim3(C_ / 16, B_), 256, 0, stream>>>(
      out_w, stats, gn_w, gn_b, out_b, w2p, biasp);

  // output GEMM (A = hb, per-batch folded Bw/bias, XCD-swizzled) + residual
  gemm_bt<1><<<dim3(C_ / 128, M_ / 128), 256, 0, stream>>>(
      hb, w2p, biasp, x, nullptr, out, nullptr, M_, C_, K_);
}

// Round 10
// 274.042 us; speedup vs baseline: 1.0564x; 1.0564x over previous
//
#include <hip/hip_runtime.h>

#define B_ 4
#define T_ 2048
#define C_ 1024
#define H_ 4
#define D_ 256
#define M_ (B_*T_)      /* 8192 */
#define N1_ (4*C_)      /* 4096 */
#define K_ C_           /* 1024 */
#define LANES_ (B_*C_)  /* 4096 */
#define CHUNK_ 32
#define NCHUNK_ (T_/CHUNK_)  /* 64 */

typedef unsigned short u16;
typedef unsigned int u32;
typedef __bf16 bf16x8 __attribute__((ext_vector_type(8)));
typedef float f32x4 __attribute__((ext_vector_type(4)));
typedef float vf4 __attribute__((ext_vector_type(4)));
typedef unsigned short u16x4 __attribute__((ext_vector_type(4)));
typedef unsigned short u16x8 __attribute__((ext_vector_type(8)));

__device__ __forceinline__ u16 f2bf(float f) {
  union { float f; u32 u; } v; v.f = f;
  u32 u = v.u;
  u32 r = (u + 0x7FFFu + ((u >> 16) & 1u)) >> 16;
  return (u16)r;
}
__device__ __forceinline__ float b2f(u16 h) {
  union { u32 u; float f; } v; v.u = ((u32)h) << 16;
  return v.f;
}

#define NCAST_ ((N1_*K_) / 2048)   /* 2048 blocks for wx_w cast */

// ---------------- merged prologue: wx_w cast + conv+SiLU ----------------
__global__ void prep_kernel(const float* __restrict__ wx_w,
                            u16* __restrict__ w1p,
                            const float* __restrict__ x, const float* __restrict__ cw,
                            const float* __restrict__ cb, u16* __restrict__ xc,
                            float* __restrict__ stats) {
  if (blockIdx.x < NCAST_) {
    int i8 = (blockIdx.x * 256 + threadIdx.x) * 8;
    int n = i8 >> 10, k8 = i8 & 1023;
    const float* src = wx_w + (size_t)(((n & 3) << 10) | (n >> 2)) * K_ + k8;
    vf4 a = *(const vf4*)src;
    vf4 b = *(const vf4*)(src + 4);
    u16x8 o;
#pragma unroll
    for (int j = 0; j < 4; ++j) { o[j] = f2bf(a[j]); o[j + 4] = f2bf(b[j]); }
    *(u16x8*)(w1p + i8) = o;
    return;
  }
  if (blockIdx.x == NCAST_ && threadIdx.x < 32) stats[threadIdx.x] = 0.f;
  int i4 = ((blockIdx.x - NCAST_) * 256 + threadIdx.x) * 4;
  int c = i4 & (C_ - 1);
  int t = (i4 >> 10) & (T_ - 1);
  vf4 acc = *(const vf4*)(cb + c);
  vf4 w0 = *(const vf4*)(cw + (size_t)c * 4);
  vf4 w1 = *(const vf4*)(cw + (size_t)(c + 1) * 4);
  vf4 w2v = *(const vf4*)(cw + (size_t)(c + 2) * 4);
  vf4 w3 = *(const vf4*)(cw + (size_t)(c + 3) * 4);
#pragma unroll
  for (int k = 0; k < 4; ++k) {
    if (t - 3 + k >= 0) {
      vf4 xv = *(const vf4*)(x + (size_t)i4 + (size_t)(k - 3) * C_);
      acc[0] = fmaf(w0[k], xv[0], acc[0]);
      acc[1] = fmaf(w1[k], xv[1], acc[1]);
      acc[2] = fmaf(w2v[k], xv[2], acc[2]);
      acc[3] = fmaf(w3[k], xv[3], acc[3]);
    }
  }
  u16x4 o;
#pragma unroll
  for (int j = 0; j < 4; ++j) {
    float s = acc[j] / (1.f + __expf(-acc[j]));
    o[j] = f2bf(s);
  }
  *(u16x4*)(xc + i4) = o;
}

// ---------------- bf16 MFMA GEMM, C[m][n] = sum_k A[m][k] * Bw[n][k] ----------------
// Final composition: verified round-0 structure, __launch_bounds__(256,3),
// DEFAULT block mapping (round-7 showed XCD swizzle inflates FETCH 2.2x).
// EPI 0: gates epilogue (bias, tanh on z) + fused passA chunk summaries.
// EPI 1: GN pre-folded per-batch weights/bias + fp32 stash + residual add.
template <int EPI>
__global__ __launch_bounds__(256, 3)
void gemm_bt(const u16* __restrict__ A, const u16* __restrict__ Bw,
             const float* __restrict__ bias, const float* __restrict__ resid,
             u16* __restrict__ obf, float* __restrict__ of32,
             f32x4* __restrict__ sSum, int M, int N, int K)
{
  __shared__ __align__(16) u16 smem[128 * 136];   // 34.8 KB; staging uses first 32 KB
  u16* a_s = smem;
  u16* b_s = smem + 128 * 64;

  const int tid  = threadIdx.x;
  const int lane = tid & 63;
  const int l15  = lane & 15;
  const int q    = lane >> 4;
  const int wave = tid >> 6;
  const int wm   = (wave >> 1) * 64;
  const int wn   = (wave & 1) * 64;
  const int bm   = blockIdx.y * 128;
  const int bn   = blockIdx.x * 128;

  if (EPI == 1) {
    // per-batch folded weights/bias (each 128-row M-tile lies in one batch)
    int batch = bm >> 11;
    Bw   += (size_t)batch * N * K;
    bias += (size_t)batch << 10;
  }

  const int srow   = wave * 8 + (lane >> 3);
  const int schunk = lane & 7;

  // per-thread bias (columns depend only on sn)
  float bias4[4];
#pragma unroll
  for (int sn = 0; sn < 4; ++sn) {
    int gcol = bn + wn + sn * 16 + l15;
    bias4[sn] = (EPI == 0) ? bias[((gcol & 3) << 10) | (gcol >> 2)] : bias[gcol];
  }
  const bool zlane = (EPI == 0) && ((l15 & 3) == 2);

  f32x4 acc[4][4];
#pragma unroll
  for (int i = 0; i < 4; ++i)
#pragma unroll
    for (int j = 0; j < 4; ++j) acc[i][j] = (f32x4){0.f, 0.f, 0.f, 0.f};

  for (int k0 = 0; k0 < K; k0 += 64) {
#pragma unroll
    for (int i = 0; i < 4; ++i) {
      int r = i * 32 + srow;
      int lc = schunk ^ (r & 7);
      const u16* ga = A  + (size_t)(bm + r) * K + k0 + lc * 8;
      const u16* gb = Bw + (size_t)(bn + r) * K + k0 + lc * 8;
      __builtin_amdgcn_global_load_lds(
          (const __attribute__((address_space(1))) u32*)ga,
          (__attribute__((address_space(3))) u32*)&a_s[(i * 32 + wave * 8) * 64],
          16, 0, 0);
      __builtin_amdgcn_global_load_lds(
          (const __attribute__((address_space(1))) u32*)gb,
          (__attribute__((address_space(3))) u32*)&b_s[(i * 32 + wave * 8) * 64],
          16, 0, 0);
    }
    __syncthreads();
#pragma unroll
    for (int kk = 0; kk < 64; kk += 32) {
      const int kc = kk >> 3;
      bf16x8 af[4], bfr[4];
#pragma unroll
      for (int s = 0; s < 4; ++s) {
        int ra = wm + s * 16 + l15;
        int ph = (kc + q) ^ (ra & 7);
        af[s] = *(const bf16x8*)&a_s[ra * 64 + ph * 8];
      }
#pragma unroll
      for (int s = 0; s < 4; ++s) {
        int rb = wn + s * 16 + l15;
        int ph = (kc + q) ^ (rb & 7);
        bfr[s] = *(const bf16x8*)&b_s[rb * 64 + ph * 8];
      }
#pragma unroll
      for (int sm = 0; sm < 4; ++sm)
#pragma unroll
        for (int sn = 0; sn < 4; ++sn)
          acc[sm][sn] = __builtin_amdgcn_mfma_f32_16x16x32_bf16(af[sm], bfr[sn], acc[sm][sn], 0, 0, 0);
    }
    __syncthreads();
  }

  if (EPI == 0) {
    // stash bf16 tile in LDS (stride 136 u16 = 272 B, 16B-aligned rows)
#pragma unroll
    for (int smi = 0; smi < 4; ++smi) {
#pragma unroll
      for (int r = 0; r < 4; ++r) {
        int lrow = wm + smi * 16 + q * 4 + r;
#pragma unroll
        for (int sni = 0; sni < 4; ++sni) {
          int lcol = wn + sni * 16 + l15;
          float v = acc[smi][sni][r] + bias4[sni];
          if (zlane) {
            float e = __expf(2.f * v);
            v = (e - 1.f) / (e + 1.f);
          }
          smem[lrow * 136 + lcol] = f2bf(v);
        }
      }
    }
    __syncthreads();
    // vectorized global stores: 8 x 16B per thread
#pragma unroll
    for (int it = 0; it < 8; ++it) {
      int flat = it * 256 + tid;               // 0..2047
      int row = flat >> 4;
      int ch  = flat & 15;
      u16x8 vv = *(const u16x8*)&smem[row * 136 + ch * 8];
      *(u16x8*)(obf + (size_t)(bm + row) * N + bn + ch * 8) = vv;
    }
    // fused passA: 32 channels x 4 chunks of 32 timesteps
    if (tid < 128) {
      int ch = tid & 31, ck = tid >> 5;
      const u16* sp = smem + (ck * 32) * 136 + ch * 4;
      float F = 0.f, Mx = -1e30f, aBc = 0.f, aBn = 0.f;
#pragma unroll 8
      for (int t = 0; t < CHUNK_; ++t) {
        u16x4 gv = *(const u16x4*)(sp + t * 136);
        float i_t = b2f(gv[0]), f_t = b2f(gv[1]), z_t = b2f(gv[2]);
        float Mf = Mx + f_t;
        float Mn = fmaxf(Mf, i_t);
        float ea = __expf(Mf - Mn), eb = __expf(i_t - Mn);
        aBc = ea * aBc + eb * z_t;
        aBn = ea * aBn + eb;
        F += f_t; Mx = Mn;
      }
      int b = bm >> 11;
      int s = ((bm & 2047) >> 5) + ck;
      int cg = (bn >> 2) + ch;
      sSum[(size_t)s * LANES_ + b * C_ + cg] = (f32x4){F, Mx, aBc, aBn};
    }
  } else {
    // two half-tiles through LDS as fp32 (64 x 132 floats = 33.8 KB)
    float* fs = (float*)smem;
#pragma unroll
    for (int h = 0; h < 2; ++h) {
      __syncthreads();
#pragma unroll
      for (int smi2 = 0; smi2 < 2; ++smi2) {
        int smi = 2 * h + smi2;
#pragma unroll
        for (int r = 0; r < 4; ++r) {
          int slot = (wm >> 1) + smi2 * 16 + q * 4 + r;   // 0..63
#pragma unroll
          for (int sni = 0; sni < 4; ++sni) {
            int lcol = wn + sni * 16 + l15;
            fs[slot * 132 + lcol] = acc[smi][sni][r] + bias4[sni];
          }
        }
      }
      __syncthreads();
#pragma unroll
      for (int it = 0; it < 8; ++it) {
        int flat = it * 256 + tid;             // 0..2047
        int slot = flat >> 5;                  // 0..63
        int c4 = (flat & 31) * 4;
        int absrow = bm + ((slot & 32) << 1) + (h << 5) + (slot & 31);
        vf4 v = *(const vf4*)&fs[slot * 132 + c4];
        vf4 rv = *(const vf4*)(resid + (size_t)absrow * N + bn + c4);
        v[0] += rv[0]; v[1] += rv[1]; v[2] += rv[2]; v[3] += rv[3];
        *(vf4*)(of32 + (size_t)absrow * N + bn + c4) = v;
      }
    }
  }
}

// ---------------- prefix: fold 64 chunk summaries per lane; float4-packed ----------------
__global__ void scan_prefix(const f32x4* __restrict__ sSum, f32x4* __restrict__ iSt) {
  int l = blockIdx.x * 256 + threadIdx.x;       // 0..4095
  float ct = 0.f, nt = 1.f, mt = 0.f;           // reference init (c=0, n=1, m=0)
#pragma unroll 8
  for (int s = 0; s < NCHUNK_; ++s) {
    int idx = s * LANES_ + l;
    f32x4 S = sSum[idx];
    iSt[idx] = (f32x4){ct, nt, mt, 0.f};
    float mf = mt + S[0];
    float mn = fmaxf(mf, S[1]);
    float a = __expf(mf - mn);
    float bcoef = __expf(S[1] - mn);
    ct = a * ct + bcoef * S[2];
    nt = a * nt + bcoef * S[3];
    mt = mn;
  }
}

// ---------------- passB: exact reference replay per chunk + fused GN stats ----------------
__global__ void scan_passB(const u16* __restrict__ gates, const f32x4* __restrict__ iSt,
                           u16* __restrict__ h, float* __restrict__ stats) {
  int tid = blockIdx.x * 256 + threadIdx.x;
  int lp = tid & 2047;
  int s = tid >> 11;
  int b = lp >> 9;
  int c2 = (lp & 511) * 2;
  const u16* g = gates + ((size_t)(b * T_ + s * CHUNK_) * C_ + c2) * 4;
  u16* hp = h + (size_t)(b * T_ + s * CHUNK_) * C_ + c2;
  int idx = s * LANES_ + b * C_ + c2;
  f32x4 S0 = iSt[idx], S1 = iSt[idx + 1];
  float cc0 = S0[0], nn0 = S0[1], mm0 = S0[2];
  float cc1 = S1[0], nn1 = S1[1], mm1 = S1[2];
  float ls = 0.f, lq = 0.f;
#pragma unroll 4
  for (int t = 0; t < CHUNK_; ++t) {
    u16x8 gv = *(const u16x8*)(g + (size_t)t * C_ * 4);   // [i0 f0 z0 o0 i1 f1 z1 o1]
    float h0, h1;
    {
      float i_t = b2f(gv[0]), f_t = b2f(gv[1]), z_t = b2f(gv[2]), o_t = b2f(gv[3]);
      float m_new = fmaxf(f_t + mm0, i_t);
      float i_p = __expf(i_t - m_new);
      float f_p = __expf(f_t + mm0 - m_new);
      cc0 = f_p * cc0 + i_p * z_t;
      nn0 = f_p * nn0 + i_p;
      mm0 = m_new;
      float sig_o = 1.f / (1.f + __expf(-o_t));
      h0 = sig_o * (cc0 / (nn0 + 1e-6f));
    }
    {
      float i_t = b2f(gv[4]), f_t = b2f(gv[5]), z_t = b2f(gv[6]), o_t = b2f(gv[7]);
      float m_new = fmaxf(f_t + mm1, i_t);
      float i_p = __expf(i_t - m_new);
      float f_p = __expf(f_t + mm1 - m_new);
      cc1 = f_p * cc1 + i_p * z_t;
      nn1 = f_p * nn1 + i_p;
      mm1 = m_new;
      float sig_o = 1.f / (1.f + __expf(-o_t));
      h1 = sig_o * (cc1 / (nn1 + 1e-6f));
    }
    u16 hb0 = f2bf(h0), hb1 = f2bf(h1);
    float v0 = b2f(hb0), v1 = b2f(hb1);
    ls += v0 + v1; lq += v0 * v0 + v1 * v1;
    *(u32*)(hp + (size_t)t * C_) = (u32)hb0 | ((u32)hb1 << 16);
  }
  __shared__ float rs[256], rq[256];
  int thr = threadIdx.x;
  rs[thr] = ls; rq[thr] = lq;
  __syncthreads();
  for (int off = 64; off > 0; off >>= 1) {
    if ((thr & 127) < off) { rs[thr] += rs[thr + off]; rq[thr] += rq[thr + off]; }
    __syncthreads();
  }
  if ((thr & 127) == 0) {
    int grp = b * 4 + (c2 >> 8);
    atomicAdd(&stats[grp * 2 + 0], rs[thr]);
    atomicAdd(&stats[grp * 2 + 1], rq[thr]);
  }
}

// ---------------- GN fold: w2p[b][o][c] = bf16(rstd*gn_w[c]*out_w[o][c]),
//                  biasp[b][o] = out_b[o] + sum_c (gn_b[c]-mean*rstd*gn_w[c])*out_w[o][c]
__global__ void gn_fold(const float* __restrict__ out_w, const float* __restrict__ stats,
                        const float* __restrict__ gn_w, const float* __restrict__ gn_b,
                        const float* __restrict__ out_b,
                        u16* __restrict__ w2p, float* __restrict__ biasp) {
  const int batch = blockIdx.y;
  const int o = blockIdx.x * 16 + (threadIdx.x >> 4);
  const int seg = threadIdx.x & 15;
  const int c0 = seg * 64;                        // 64-col span, never crosses a group
  const int grp = batch * 4 + (c0 >> 8);
  const float inv_n = 1.f / (float)(T_ * D_);
  float mean = stats[grp * 2 + 0] * inv_n;
  float var  = stats[grp * 2 + 1] * inv_n - mean * mean;
  float rstd = rsqrtf(var + 1e-5f);
  const float* wrow = out_w + (size_t)o * C_;
  u16* wdst = w2p + ((size_t)batch * C_ + o) * C_;
  float acc = 0.f;
#pragma unroll 4
  for (int c = c0; c < c0 + 64; c += 4) {
    vf4 w  = *(const vf4*)(wrow + c);
    vf4 gw = *(const vf4*)(gn_w + c);
    vf4 gb = *(const vf4*)(gn_b + c);
    u16x4 ov;
#pragma unroll
    for (int j = 0; j < 4; ++j) {
      float s1 = rstd * gw[j];
      ov[j] = f2bf(s1 * w[j]);
      acc = fmaf(gb[j] - mean * s1, w[j], acc);
    }
    *(u16x4*)(wdst + c) = ov;
  }
  __shared__ float red[256];
  red[threadIdx.x] = acc;
  __syncthreads();
  for (int off = 8; off > 0; off >>= 1) {
    if (seg < off) red[threadIdx.x] += red[threadIdx.x + off];
    __syncthreads();
  }
  if (seg == 0) biasp[batch * C_ + o] = out_b[o] + red[threadIdx.x];
}

extern "C" void kernel_launch(void* const* d_in, const int* in_sizes, int n_in,
                              void* d_out, int out_size, void* d_ws, size_t ws_size,
                              hipStream_t stream) {
  const float* x      = (const float*)d_in[0];
  const float* conv_w = (const float*)d_in[1];
  const float* conv_b = (const float*)d_in[2];
  const float* wx_w   = (const float*)d_in[3];
  const float* wx_b   = (const float*)d_in[4];
  const float* gn_w   = (const float*)d_in[5];
  const float* gn_b   = (const float*)d_in[6];
  const float* out_w  = (const float*)d_in[7];
  const float* out_b  = (const float*)d_in[8];
  float* out = (float*)d_out;

  char* p = (char*)d_ws;
  u16* xc    = (u16*)p; p += (size_t)M_ * K_ * 2;      // 16.8 MB
  u16* w1    = (u16*)p; p += (size_t)N1_ * K_ * 2;     // 8.4 MB (permuted)
  u16* gts   = (u16*)p; p += (size_t)M_ * N1_ * 2;     // 67.1 MB (interleaved c*4+g)
  u16* hb    = (u16*)p; p += (size_t)M_ * C_ * 2;      // 16.8 MB
  u16* w2p   = (u16*)p; p += (size_t)B_ * C_ * C_ * 2; // 8.4 MB (per-batch folded)
  float* biasp = (float*)p; p += (size_t)B_ * C_ * 4;  // 16 KB
  float* stats = (float*)p; p += 256;
  const int nsum = LANES_ * NCHUNK_;                   // 256K
  f32x4* sSum = (f32x4*)p; p += (size_t)nsum * 16;     // 4 MB
  f32x4* iSt  = (f32x4*)p; p += (size_t)nsum * 16;     // 4 MB

  // merged prologue: wx_w cast + conv/silu (also zeroes stats)
  prep_kernel<<<NCAST_ + (M_ * C_) / 1024, 256, 0, stream>>>(
      wx_w, w1, x, conv_w, conv_b, xc, stats);

  // gates GEMM + fused passA
  gemm_bt<0><<<dim3(N1_ / 128, M_ / 128), 256, 0, stream>>>(
      xc, w1, wx_b, nullptr, gts, nullptr, sSum, M_, N1_, K_);

  // prefix + replay
  scan_prefix<<<LANES_ / 256, 256, 0, stream>>>(sSum, iSt);
  scan_passB<<<(2048 * NCHUNK_) / 256, 256, 0, stream>>>(gts, iSt, hb, stats);

  // fold GroupNorm into per-batch output weights + bias
  gn_fold<<<dim3(C_ / 16, B_), 256, 0, stream>>>(
      out_w, stats, gn_w, gn_b, out_b, w2p, biasp);

  // output GEMM (A = hb, per-batch folded Bw/bias) + residual
  gemm_bt<1><<<dim3(C_ / 128, M_ / 128), 256, 0, stream>>>(
      hb, w2p, biasp, x, nullptr, out, nullptr, M_, C_, K_);
}